// Round 2
// baseline (65.875 us; speedup 1.0000x reference)
//
#include <hip/hip_runtime.h>

// Problem constants (from reference):
//   x: (B=32, 1, L=16000) fp32
//   kernels_real/imag: (C=40, K=128) fp32
//   out = circular_conv(x, kr + i*ki) sampled every STRIDE=128
//       -> (B, C, 125) complex64.
// Output layout is resolved at runtime from out_size:
//   320000 -> planar: [all re (160000) | all im (160000)]
//   160000 -> real part only
//   else   -> interleaved (re,im) pairs
#define BB     32
#define CC     40
#define LL     16000
#define KK     128
#define MM     125      // LS / STRIDE
#define KPAD   129      // LDS stride: bank = (c + k) % 32 -> <=2-way aliasing (free)
#define NOUT   (BB * CC * MM)   // 160000 complex outputs

__global__ __launch_bounds__(256) void ISAC_conv_kernel(
    const float* __restrict__ x,     // B*L
    const float* __restrict__ kr,    // C*K
    const float* __restrict__ ki,    // C*K
    float*       __restrict__ out,   // layout per `mode`
    int mode)                        // 0=planar, 1=real-only, 2=interleaved
{
    __shared__ float skr[CC * KPAD];
    __shared__ float ski[CC * KPAD];

    // Stage all kernels into LDS (coalesced; ~41 KB total)
    for (int i = threadIdx.x; i < CC * KK; i += 256) {
        int c = i >> 7;      // i / 128
        int k = i & 127;     // i % 128
        skr[c * KPAD + k] = kr[i];
        ski[c * KPAD + k] = ki[i];
    }
    __syncthreads();

    // One thread per complex output; c fastest so a wave's 64 lanes read
    // (near-)identical x addresses each iteration -> broadcast loads.
    int id = blockIdx.x * 256 + threadIdx.x;       // 0 .. 159999 (exact)
    int c  = id % CC;
    int t  = id / CC;                              // = b*125 + m
    int m  = t % MM;
    int b  = t / MM;

    const float* xb  = x   + b * LL;
    const float* kcr = skr + c * KPAD;
    const float* kci = ski + c * KPAD;
    const int base = m * KK;                       // x index at tap j=0

    float accr = 0.f, acci = 0.f;
#pragma unroll 8
    for (int j = 0; j < KK; ++j) {
        int idx = base - j;
        idx += (idx >> 31) & LL;                   // circular wrap (m==0 only)
        float xv = xb[idx];
        accr = fmaf(xv, kcr[j], accr);
        acci = fmaf(xv, kci[j], acci);
    }

    int oidx = (b * CC + c) * MM + m;              // (b, c, m) flat complex index
    if (mode == 0) {
        out[oidx]        = accr;                   // planar re block
        out[NOUT + oidx] = acci;                   // planar im block
    } else if (mode == 1) {
        out[oidx] = accr;                          // real part only
    } else {
        reinterpret_cast<float2*>(out)[oidx] = make_float2(accr, acci);
    }
}

extern "C" void kernel_launch(void* const* d_in, const int* in_sizes, int n_in,
                              void* d_out, int out_size, void* d_ws, size_t ws_size,
                              hipStream_t stream) {
    const float* x  = (const float*)d_in[0];
    const float* kr = (const float*)d_in[1];
    const float* ki = (const float*)d_in[2];
    float* out = (float*)d_out;

    int mode;
    if (out_size == 2 * NOUT)      mode = 0;   // planar re|im
    else if (out_size == NOUT)     mode = 1;   // real only
    else                           mode = 2;   // interleaved fallback

    const int total = NOUT;                        // 160000 outputs
    const int block = 256;
    const int grid  = (total + block - 1) / block; // 625, exact

    ISAC_conv_kernel<<<grid, block, 0, stream>>>(x, kr, ki, out, mode);
}

// Round 3
// 63.020 us; speedup vs baseline: 1.0453x; 1.0453x over previous
//
#include <hip/hip_runtime.h>

// out[b,c,m] = sum_{j=0}^{127} x[b, (128m - j) mod 16000] * (kr[c,j] + i*ki[c,j])
//   x: (32, 1, 16000) fp32; kernels: (40, 128) fp32 each
//   out: (32, 40, 125) complex64 -> planar [all re | all im] (confirmed round 2)
#define BB     32
#define CC     40
#define LL     16000
#define KK     128
#define MM     125
#define KPAD2  129                  // float2 row stride: bank = 2c mod 32 -> <=3-way
#define NOUT   (BB * CC * MM)       // 160000 complex outputs

__global__ __launch_bounds__(256) void ISAC_conv_kernel(
    const float* __restrict__ x,     // B*L
    const float* __restrict__ kr,    // C*K
    const float* __restrict__ ki,    // C*K
    float*       __restrict__ out,   // layout per `mode`
    int mode)                        // 0=planar, 1=real-only, 2=interleaved
{
    __shared__ float2 skc[CC * KPAD2];   // (kr, ki) interleaved, ~41.3 KB

    // Stage kernels into LDS, interleaved as float2 (coalesced reads)
    for (int i = threadIdx.x; i < CC * KK; i += 256) {
        int c = i >> 7;      // i / 128
        int k = i & 127;     // i % 128
        skc[c * KPAD2 + k] = make_float2(kr[i], ki[i]);
    }
    __syncthreads();

    // One thread per complex output; c fastest -> 64 lanes span 2 t values,
    // so each global x load touches <=2 cache lines (broadcast-like).
    int id = blockIdx.x * 256 + threadIdx.x;       // 0 .. 159999 (exact grid)
    int c  = id % CC;
    int t  = id / CC;                              // = b*125 + m
    int m  = t % MM;
    int b  = t / MM;

    const float2* kc = skc + c * KPAD2;
    const float*  xb = x + b * LL;
    const int base = m * KK;

    // Wrap hoisted: for j>=1, index (base - j) mod LL == (m==0 ? LL - j : base - j).
    // j=0 reads xb[base] (always valid). Loop body then has NO per-tap addr math:
    // p[-j] and kc[j] compile to immediate-offset loads under full unroll.
    const float* p = xb + (m == 0 ? LL : base);

    float2 k0  = kc[0];
    float  xv0 = xb[base];
    float accr = xv0 * k0.x;
    float acci = xv0 * k0.y;

#pragma unroll
    for (int j = 1; j < KK; ++j) {
        float  xv = p[-j];                         // global_load offset:-4j
        float2 kv = kc[j];                         // ds_read_b64 offset:8j
        accr = fmaf(xv, kv.x, accr);
        acci = fmaf(xv, kv.y, acci);
    }

    int oidx = (b * CC + c) * MM + m;              // (b, c, m) flat complex index
    if (mode == 0) {
        out[oidx]        = accr;                   // planar re block
        out[NOUT + oidx] = acci;                   // planar im block
    } else if (mode == 1) {
        out[oidx] = accr;
    } else {
        reinterpret_cast<float2*>(out)[oidx] = make_float2(accr, acci);
    }
}

extern "C" void kernel_launch(void* const* d_in, const int* in_sizes, int n_in,
                              void* d_out, int out_size, void* d_ws, size_t ws_size,
                              hipStream_t stream) {
    const float* x  = (const float*)d_in[0];
    const float* kr = (const float*)d_in[1];
    const float* ki = (const float*)d_in[2];
    float* out = (float*)d_out;

    int mode;
    if (out_size == 2 * NOUT)      mode = 0;   // planar re|im (confirmed)
    else if (out_size == NOUT)     mode = 1;
    else                           mode = 2;

    const int total = NOUT;
    const int block = 256;
    const int grid  = (total + block - 1) / block; // 625, exact

    ISAC_conv_kernel<<<grid, block, 0, stream>>>(x, kr, ki, out, mode);
}

// Round 4
// 62.264 us; speedup vs baseline: 1.0580x; 1.0121x over previous
//
#include <hip/hip_runtime.h>

// out[b,c,m] = sum_{j=0}^{127} x[b, (128m - j) mod 16000] * (kr[c,j] + i*ki[c,j])
//   x: (32, 1, 16000) fp32; kernels: (40, 128) fp32 each
//   out: (32, 40, 125) complex64 -> planar [all re | all im] (confirmed round 2)
//
// Round 4: kernels packed as (bf16 re, bf16 im) in ONE dword in LDS.
//   LDS 41.3 KB -> 20.6 KB: 3 -> ~6 resident blocks/CU, doubling latency hiding
//   (theory: kernel is latency-bound, not instruction-bound — round 3's VALU
//   diet was near-neutral). bf16 RNE on kernels only; x and accum stay fp32.
#define BB     32
#define CC     40
#define LL     16000
#define KK     128
#define MM     125
#define KPAD   129                  // dword row stride: bank = (c+j) mod 32 -> <=2-way (free)
#define NOUT   (BB * CC * MM)       // 160000 complex outputs

__global__ __launch_bounds__(256) void ISAC_conv_kernel(
    const float* __restrict__ x,     // B*L
    const float* __restrict__ kr,    // C*K
    const float* __restrict__ ki,    // C*K
    float*       __restrict__ out,   // layout per `mode`
    int mode)                        // 0=planar, 1=real-only, 2=interleaved
{
    __shared__ unsigned int skc[CC * KPAD];   // packed (bf16 re | bf16 im), 20.6 KB

    // Stage kernels into LDS, RNE-rounded to bf16 and packed 2-per-dword
    for (int i = threadIdx.x; i < CC * KK; i += 256) {
        int c = i >> 7;      // i / 128
        int k = i & 127;     // i % 128
        unsigned int br = __float_as_uint(kr[i]);
        unsigned int bi = __float_as_uint(ki[i]);
        unsigned int hr = (br + 0x7FFFu + ((br >> 16) & 1u)) & 0xFFFF0000u; // re in hi16
        unsigned int hi = (bi + 0x7FFFu + ((bi >> 16) & 1u)) >> 16;         // im in lo16
        skc[c * KPAD + k] = hr | hi;
    }
    __syncthreads();

    // One thread per complex output; c fastest -> 64 lanes span <=2 t values,
    // so each global x load touches <=2 cache lines (broadcast-like).
    int id = blockIdx.x * 256 + threadIdx.x;       // 0 .. 159999 (exact grid)
    int c  = id % CC;
    int t  = id / CC;                              // = b*125 + m
    int m  = t % MM;
    int b  = t / MM;

    const unsigned int* kc = skc + c * KPAD;
    const float*        xb = x + b * LL;
    const int base = m * KK;

    // Wrap hoisted: for j>=1, (base - j) mod LL == (m==0 ? LL - j : base - j).
    // Loop body has no per-tap address math: immediate-offset loads under unroll.
    const float* p = xb + (m == 0 ? LL : base);

    unsigned int u0 = kc[0];
    float xv0  = xb[base];
    float accr = xv0 * __uint_as_float(u0 & 0xFFFF0000u);
    float acci = xv0 * __uint_as_float(u0 << 16);

#pragma unroll
    for (int j = 1; j < KK; ++j) {
        float        xv = p[-j];                   // global_load offset:-4j
        unsigned int u  = kc[j];                   // ds_read_b32 offset:4j
        accr = fmaf(xv, __uint_as_float(u & 0xFFFF0000u), accr);
        acci = fmaf(xv, __uint_as_float(u << 16),         acci);
    }

    int oidx = (b * CC + c) * MM + m;              // (b, c, m) flat complex index
    if (mode == 0) {
        out[oidx]        = accr;                   // planar re block
        out[NOUT + oidx] = acci;                   // planar im block
    } else if (mode == 1) {
        out[oidx] = accr;
    } else {
        reinterpret_cast<float2*>(out)[oidx] = make_float2(accr, acci);
    }
}

extern "C" void kernel_launch(void* const* d_in, const int* in_sizes, int n_in,
                              void* d_out, int out_size, void* d_ws, size_t ws_size,
                              hipStream_t stream) {
    const float* x  = (const float*)d_in[0];
    const float* kr = (const float*)d_in[1];
    const float* ki = (const float*)d_in[2];
    float* out = (float*)d_out;

    int mode;
    if (out_size == 2 * NOUT)      mode = 0;   // planar re|im (confirmed)
    else if (out_size == NOUT)     mode = 1;
    else                           mode = 2;

    const int total = NOUT;
    const int block = 256;
    const int grid  = (total + block - 1) / block; // 625, exact

    ISAC_conv_kernel<<<grid, block, 0, stream>>>(x, kr, ki, out, mode);
}